// Round 15
// baseline (183.655 us; speedup 1.0000x reference)
//
#include <hip/hip_runtime.h>
#include <math.h>
#include <stdint.h>

#define B_   2
#define N_   10000
#define E_   160000
#define HID_ 128
#define ED_  32
#define NH_  8
#define HD_  16
#define ROWS_ (B_ * N_)   // 20000

using half2_t = __attribute__((ext_vector_type(2))) _Float16;
using f16x8   = __attribute__((ext_vector_type(8))) _Float16;
using f32x4   = __attribute__((ext_vector_type(4))) float;

__device__ __forceinline__ half2_t f2h2(float a, float b) {
    return __builtin_bit_cast(half2_t, __builtin_amdgcn_cvt_pkrtz(a, b));
}
__device__ __forceinline__ uint32_t pkh2(float a, float b) {
    return __builtin_bit_cast(uint32_t, __builtin_amdgcn_cvt_pkrtz(a, b));
}
__device__ __forceinline__ uint16_t f2h(float v) {
    return __builtin_bit_cast(uint16_t, (_Float16)v);
}

// ---------------- CSR build ----------------

__global__ void hist_kernel(const int* __restrict__ ei, int* __restrict__ deg, int E) {
    int e = blockIdx.x * 256 + threadIdx.x;
    if (e < E) atomicAdd(&deg[ei[2 * e + 1]], 1);
}

__global__ __launch_bounds__(256) void scan_kernel(const int* __restrict__ deg,
                                                   int* __restrict__ off, int N) {
    __shared__ int sums[256];
    int t = threadIdx.x;
    int chunk = (N + 255) / 256;
    int s0 = t * chunk, s1 = min(N, s0 + chunk);
    int s = 0;
    for (int i = s0; i < s1; ++i) s += deg[i];
    sums[t] = s;
    __syncthreads();
    #pragma unroll
    for (int d = 1; d < 256; d <<= 1) {
        int v = (t >= d) ? sums[t - d] : 0;
        __syncthreads();
        sums[t] += v;
        __syncthreads();
    }
    if (t == 255) off[N] = sums[255];
    int run = sums[t] - s;
    for (int i = s0; i < s1; ++i) { off[i] = run; run += deg[i]; }
}

__global__ void fill_kernel(const int* __restrict__ ei, const int* __restrict__ off,
                            int* __restrict__ cursor, int* __restrict__ csr,
                            int* __restrict__ srcs, int E) {
    int e = blockIdx.x * 256 + threadIdx.x;
    if (e < E) {
        int2 se = *(const int2*)(ei + 2 * e);   // x=src, y=dst
        int p = atomicAdd(&cursor[se.y], 1);
        int o = off[se.y] + p;
        csr[o] = e;
        srcs[o] = se.x;
    }
}

// ---------------- qkvs MFMA GEMM, single pass (R14-proven) ----------------

#define GM 64
#define LDA 68

__global__ __launch_bounds__(256) void qkvs_kernel(
    const float* __restrict__ h,
    const float* __restrict__ Wq, const float* __restrict__ bq,
    const float* __restrict__ Wk, const float* __restrict__ bk,
    const float* __restrict__ Wv, const float* __restrict__ bv,
    const float* __restrict__ Ws, const float* __restrict__ bs,
    const float* __restrict__ ba,
    float* __restrict__ Q, uint16_t* __restrict__ Kv16, float* __restrict__ S)
{
    __shared__ uint32_t As[GM * LDA];
    __shared__ uint32_t Bs[128 * LDA];
    __shared__ float bsm[512];

    int tid = threadIdx.x;
    int lane = tid & 63;
    int wave = tid >> 6;
    int row0 = blockIdx.x * GM;

    for (int f = tid; f < 512; f += 256) {
        float v;
        if (f < 128)      v = bq[f];
        else if (f < 256) v = bk[f - 128];
        else if (f < 384) v = bv[f - 256];
        else              v = bs[f - 384] + ba[f - 384];
        bsm[f] = v;
    }

    for (int f = tid; f < GM * 32; f += 256) {
        int r = f >> 5, c4 = f & 31;
        long row = row0 + r;
        float4 hv = (row < ROWS_) ? *(const float4*)(h + row * HID_ + c4 * 4)
                                  : make_float4(0.f, 0.f, 0.f, 0.f);
        As[r * LDA + c4 * 2]     = pkh2(hv.x, hv.y);
        As[r * LDA + c4 * 2 + 1] = pkh2(hv.z, hv.w);
    }

    int lq = lane & 15;
    int ar = wave * 16 + lq;

    for (int jc = 0; jc < 4; ++jc) {
        int J0 = jc * 128;
        __syncthreads();
        for (int f = tid; f < 128 * 32; f += 256) {
            int jr = f >> 5, c4 = f & 31;
            int J = J0 + jr;
            const float* Wp;
            if (J < 128)      Wp = Wq + (long)J * HID_;
            else if (J < 256) Wp = Wk + (long)(J - 128) * HID_;
            else if (J < 384) Wp = Wv + (long)(J - 256) * HID_;
            else              Wp = Ws + (long)(J - 384) * HID_;
            float4 wv = *(const float4*)(Wp + c4 * 4);
            Bs[jr * LDA + c4 * 2]     = pkh2(wv.x, wv.y);
            Bs[jr * LDA + c4 * 2 + 1] = pkh2(wv.z, wv.w);
        }
        __syncthreads();

        f32x4 acc[8];
        #pragma unroll
        for (int nt = 0; nt < 8; ++nt) {
            float c = bsm[J0 + nt * 16 + lq];
            acc[nt] = (f32x4){ c, c, c, c };
        }

        #pragma unroll
        for (int ks = 0; ks < 4; ++ks) {
            f16x8 a = *(const f16x8*)(As + ar * LDA + ks * 16 + (lane >> 4) * 4);
            #pragma unroll
            for (int nt = 0; nt < 8; ++nt) {
                f16x8 b = *(const f16x8*)(Bs + (nt * 16 + lq) * LDA + ks * 16 + (lane >> 4) * 4);
                acc[nt] = __builtin_amdgcn_mfma_f32_16x16x32_f16(a, b, acc[nt], 0, 0, 0);
            }
        }

        #pragma unroll
        for (int nt = 0; nt < 8; ++nt) {
            int J = J0 + nt * 16 + lq;
            long rbase = row0 + wave * 16 + (lane >> 4) * 4;
            #pragma unroll
            for (int r = 0; r < 4; ++r) {
                long row = rbase + r;
                if (row < ROWS_) {
                    float v = acc[nt][r];
                    if (J < 128)      Q[row * 128 + J] = v;
                    else if (J < 256) Kv16[row * 256 + 2 * (J - 128)] = f2h(v);      // K lo
                    else if (J < 384) Kv16[row * 256 + 2 * (J - 256) + 1] = f2h(v);  // V hi
                    else              S[row * 128 + (J - 384)] = v;
                }
            }
        }
    }
}

// ---------------- DPP reduces ----------------

template <int CTRL>
__device__ __forceinline__ float dpp_add(float x) {
    int y = __builtin_amdgcn_mov_dpp(__float_as_int(x), CTRL, 0xF, 0xF, true);
    return x + __int_as_float(y);
}
__device__ __forceinline__ float hsum8(float p) {   // sum over aligned 8-lane group
    p = dpp_add<0xB1>(p);   // quad_perm xor1
    p = dpp_add<0x4E>(p);   // quad_perm xor2
    p = dpp_add<0x141>(p);  // row_half_mirror (xor across the two quads of the 8-group)
    return p;
}
__device__ __forceinline__ float hsum16(float p) {
    p = dpp_add<0xB1>(p);
    p = dpp_add<0x4E>(p);
    p = dpp_add<0x141>(p);
    p = dpp_add<0x140>(p);  // row_mirror
    return p;
}

// ---------------- edge aggregation: SINGLE-WAVE blocks, 2 nodes/block ----------------
// Thread t owns features 2t, 2t+1 (same head = t>>3). No __syncthreads anywhere.

#define NPB 2
#define CHUNK 64
#define EAS 18   // dwords per staged f16 ea row (16 data + 2 pad)

__global__ __launch_bounds__(64, 4) void node_kernel(
    const float* __restrict__ edge_attr,
    const float* __restrict__ Q, const uint32_t* __restrict__ KVp,  // [row][128] dwords
    const float* __restrict__ We, const float* __restrict__ be,
    const float* __restrict__ attn_vec,
    const int* __restrict__ off, const int* __restrict__ csr,
    const int* __restrict__ srcs,
    uint16_t* __restrict__ aggh)
{
    int n0 = blockIdx.x * NPB;
    int b  = blockIdx.y;
    int t  = threadIdx.x;           // 0..63, features 2t and 2t+1
    long bN = (long)b * N_;

    __shared__ int sL[CHUNK];
    __shared__ uint32_t eaL[CHUNK * EAS];

    // We rows 2t and 2t+1 in f16 registers
    half2_t we0[16], we1[16];
    {
        const float4* W0 = (const float4*)(We + (long)(2 * t) * ED_);
        const float4* W1 = (const float4*)(We + (long)(2 * t + 1) * ED_);
        #pragma unroll
        for (int c = 0; c < 8; ++c) {
            float4 w = W0[c];
            we0[2 * c]     = f2h2(w.x, w.y);
            we0[2 * c + 1] = f2h2(w.z, w.w);
            float4 v = W1[c];
            we1[2 * c]     = f2h2(v.x, v.y);
            we1[2 * c + 1] = f2h2(v.z, v.w);
        }
    }
    float2 bev = *(const float2*)(be + 2 * t);
    float2 av  = *(const float2*)(attn_vec + 2 * t);
    av.x *= 0.25f; av.y *= 0.25f;

    float2 q0 = *(const float2*)(Q + (bN + n0 + 0) * 128 + 2 * t);
    float2 q1 = *(const float2*)(Q + (bN + n0 + 1) * 128 + 2 * t);

    int o0 = off[n0];
    int c1 = off[n0 + 1] - o0, c2 = off[n0 + 2] - o0;
    int total = c2;

    const float* eab = edge_attr + (long)b * E_ * ED_;
    const uint32_t* KVb = KVp + bN * 128;

    float a00 = 0.f, a01 = 0.f, den0 = 0.f;   // node0: feat f0, f1
    float a10 = 0.f, a11 = 0.f, den1 = 0.f;   // node1

    auto edge_body = [&](int i, const float2& qg, float& af0, float& af1, float& deng) {
        int s = sL[i];
        uint2 kvu = *(const uint2*)(KVb + (long)s * 128 + 2 * t);   // dwordx2: feats 2t,2t+1
        half2_t kv0 = __builtin_bit_cast(half2_t, kvu.x);           // x=K, y=V (feat 2t)
        half2_t kv1 = __builtin_bit_cast(half2_t, kvu.y);
        const half2_t* ea = (const half2_t*)(eaL + i * EAS);
        float e0a = bev.x, e0b = 0.f, e1a = bev.y, e1b = 0.f;
        #pragma unroll
        for (int c = 0; c < 8; ++c) {
            half2_t eac = ea[c], ead = ea[c + 8];
            e0a = __builtin_amdgcn_fdot2(we0[c], eac, e0a, false);
            e0b = __builtin_amdgcn_fdot2(we0[c + 8], ead, e0b, false);
            e1a = __builtin_amdgcn_fdot2(we1[c], eac, e1a, false);
            e1b = __builtin_amdgcn_fdot2(we1[c + 8], ead, e1b, false);
        }
        float ej0 = e0a + e0b;
        float ej1 = e1a + e1b;
        float y0 = qg.x + (float)kv0.x + ej0;
        float y1 = qg.y + (float)kv1.x + ej1;
        float t0 = 1.f - 2.f * __builtin_amdgcn_rcpf(__expf(2.f * y0) + 1.f);
        float t1 = 1.f - 2.f * __builtin_amdgcn_rcpf(__expf(2.f * y1) + 1.f);
        float p = hsum8(t0 * av.x + t1 * av.y);   // head sum: 8 lanes x 2 feats = 16
        float ex = __expf(p);
        deng += ex;
        af0 += ex * ((float)kv0.y + ej0);
        af1 += ex * ((float)kv1.y + ej1);
    };

    auto range_loop = [&](int lo, int hi, const float2& qg,
                          float& af0, float& af1, float& deng) {
        int i = lo;
        for (; i + 3 < hi; i += 4) {
            edge_body(i, qg, af0, af1, deng);
            edge_body(i + 1, qg, af0, af1, deng);
            edge_body(i + 2, qg, af0, af1, deng);
            edge_body(i + 3, qg, af0, af1, deng);
        }
        for (; i < hi; ++i) edge_body(i, qg, af0, af1, deng);
    };

    for (int tau = 0; tau < total; tau += CHUNK) {
        int rows = min(total - tau, CHUNK);
        // single wave: no barriers needed; compiler orders LDS via lgkmcnt
        if (t < rows) sL[t] = srcs[o0 + tau + t];
        for (int idx = t; idx < rows * 8; idx += 64) {
            int r = idx >> 3, c = idx & 7;
            int e = csr[o0 + tau + r];   // L1-hot
            float4 f = *(const float4*)(eab + (long)e * ED_ + c * 4);
            eaL[r * EAS + 2 * c]     = pkh2(f.x, f.y);
            eaL[r * EAS + 2 * c + 1] = pkh2(f.z, f.w);
        }

        range_loop(max(0 - tau, 0),  min(c1 - tau, rows), q0, a00, a01, den0);
        range_loop(max(c1 - tau, 0), min(c2 - tau, rows), q1, a10, a11, den1);
    }

    uint32_t* aggp = (uint32_t*)aggh;
    {
        float r0 = (c1 > 0) ? __builtin_amdgcn_rcpf(den0) : 0.f;
        float r1 = (c2 > c1) ? __builtin_amdgcn_rcpf(den1) : 0.f;
        aggp[(bN + n0 + 0) * 64 + t] = pkh2(a00 * r0, a01 * r0);
        aggp[(bN + n0 + 1) * 64 + t] = pkh2(a10 * r1, a11 * r1);
    }
}

// ---------------- wa + gelu + residual + LayerNorm, fused (R14-proven) ----------------

__global__ __launch_bounds__(256) void wa_ln_kernel(
    const uint16_t* __restrict__ aggh,   // [row][128] f16
    const float* __restrict__ Wa,
    const float* __restrict__ S, const float* __restrict__ h,
    const float* __restrict__ ln_g, const float* __restrict__ ln_b,
    float* __restrict__ out)
{
    __shared__ uint32_t As[GM * LDA];
    __shared__ uint32_t Bs[128 * LDA];

    int tid = threadIdx.x;
    int lane = tid & 63;
    int wave = tid >> 6;
    int row0 = blockIdx.x * GM;

    const uint32_t* Xa = (const uint32_t*)aggh;
    for (int f = tid; f < GM * 16; f += 256) {
        int r = f >> 4, c = f & 15;
        long row = row0 + r;
        uint4 v = (row < ROWS_) ? *(const uint4*)(Xa + row * 64 + c * 4)
                                : make_uint4(0u, 0u, 0u, 0u);
        *(uint4*)(&As[r * LDA + c * 4]) = v;
    }
    for (int f = tid; f < 128 * 32; f += 256) {
        int jr = f >> 5, c4 = f & 31;
        float4 wv = *(const float4*)(Wa + (long)jr * HID_ + c4 * 4);
        Bs[jr * LDA + c4 * 2]     = pkh2(wv.x, wv.y);
        Bs[jr * LDA + c4 * 2 + 1] = pkh2(wv.z, wv.w);
    }
    __syncthreads();

    f32x4 acc[8];
    #pragma unroll
    for (int nt = 0; nt < 8; ++nt) acc[nt] = (f32x4){ 0.f, 0.f, 0.f, 0.f };

    int lq = lane & 15;
    int ar = wave * 16 + lq;
    #pragma unroll
    for (int ks = 0; ks < 4; ++ks) {
        f16x8 a = *(const f16x8*)(As + ar * LDA + ks * 16 + (lane >> 4) * 4);
        #pragma unroll
        for (int nt = 0; nt < 8; ++nt) {
            f16x8 b = *(const f16x8*)(Bs + (nt * 16 + lq) * LDA + ks * 16 + (lane >> 4) * 4);
            acc[nt] = __builtin_amdgcn_mfma_f32_16x16x32_f16(a, b, acc[nt], 0, 0, 0);
        }
    }

    float gJ[8], bJ[8];
    #pragma unroll
    for (int nt = 0; nt < 8; ++nt) {
        int J = nt * 16 + lq;
        gJ[nt] = ln_g[J];
        bJ[nt] = ln_b[J];
    }
    long rbase = row0 + wave * 16 + (lane >> 4) * 4;
    #pragma unroll
    for (int r = 0; r < 4; ++r) {
        long row = rbase + r;
        if (row < ROWS_) {
            float xv[8];
            float sum = 0.f, sum2 = 0.f;
            #pragma unroll
            for (int nt = 0; nt < 8; ++nt) {
                int J = nt * 16 + lq;
                float upd = acc[nt][r] + S[row * 128 + J];
                float ge = 0.5f * upd * (1.f + erff(upd * 0.70710678118654752f));
                float x = h[row * 128 + J] + ge;
                xv[nt] = x;
                sum += x;
                sum2 += x * x;
            }
            sum = hsum16(sum);
            sum2 = hsum16(sum2);
            float mu = sum * (1.f / 128.f);
            float var = sum2 * (1.f / 128.f) - mu * mu;
            float rs = rsqrtf(var + 1e-5f);
            #pragma unroll
            for (int nt = 0; nt < 8; ++nt)
                out[row * 128 + nt * 16 + lq] = (xv[nt] - mu) * rs * gJ[nt] + bJ[nt];
        }
    }
}

// ---------------- launch ----------------

extern "C" void kernel_launch(void* const* d_in, const int* in_sizes, int n_in,
                              void* d_out, int out_size, void* d_ws, size_t ws_size,
                              hipStream_t stream) {
    const float* h         = (const float*)d_in[0];
    const float* edge_attr = (const float*)d_in[1];
    const int*   ei        = (const int*)  d_in[2];
    const float* Wq = (const float*)d_in[3];
    const float* bq = (const float*)d_in[4];
    const float* Wk = (const float*)d_in[5];
    const float* bk = (const float*)d_in[6];
    const float* Wv = (const float*)d_in[7];
    const float* bv = (const float*)d_in[8];
    const float* We = (const float*)d_in[9];
    const float* be = (const float*)d_in[10];
    const float* attn_vec = (const float*)d_in[11];
    const float* Ws = (const float*)d_in[12];
    const float* bs = (const float*)d_in[13];
    const float* Wa = (const float*)d_in[14];
    const float* ba = (const float*)d_in[15];
    const float* ln_g = (const float*)d_in[16];
    const float* ln_b = (const float*)d_in[17];
    float* out = (float*)d_out;

    size_t p = 0;
    auto alloc = [&](size_t bytes) { size_t r = p; p += (bytes + 255) & ~(size_t)255; return r; };
    char* ws = (char*)d_ws;
    float*    Q    = (float*)(ws + alloc((size_t)ROWS_ * 128 * 4));
    uint16_t* Kv16 = (uint16_t*)(ws + alloc((size_t)ROWS_ * 256 * 2));
    float*    S    = (float*)(ws + alloc((size_t)ROWS_ * 128 * 4));
    uint16_t* aggh = (uint16_t*)(ws + alloc((size_t)ROWS_ * 128 * 2));
    int* dc     = (int*)(ws + alloc((size_t)2 * N_ * 4));
    int* off    = (int*)(ws + alloc((size_t)(N_ + 1) * 4));
    int* csr    = (int*)(ws + alloc((size_t)E_ * 4));
    int* srcs   = (int*)(ws + alloc((size_t)E_ * 4));
    int* deg = dc;
    int* cursor = dc + N_;
    (void)ws_size;

    hipMemsetAsync(dc, 0, (size_t)2 * N_ * 4, stream);
    hist_kernel<<<(E_ + 255) / 256, 256, 0, stream>>>(ei, deg, E_);
    scan_kernel<<<1, 256, 0, stream>>>(deg, off, N_);
    fill_kernel<<<(E_ + 255) / 256, 256, 0, stream>>>(ei, off, cursor, csr, srcs, E_);

    qkvs_kernel<<<(ROWS_ + GM - 1) / GM, 256, 0, stream>>>(h, Wq, bq, Wk, bk, Wv, bv,
                                                           Ws, bs, ba, Q, Kv16, S);

    dim3 grid(N_ / NPB, B_);
    node_kernel<<<grid, 64, 0, stream>>>(edge_attr, Q, (const uint32_t*)Kv16,
                                         We, be, attn_vec, off, csr, srcs, aggh);

    wa_ln_kernel<<<(ROWS_ + GM - 1) / GM, 256, 0, stream>>>(aggh, Wa, S, h,
                                                            ln_g, ln_b, out);
}